// Round 4
// baseline (247.300 us; speedup 1.0000x reference)
//
#include <hip/hip_runtime.h>
#include <hip/hip_bf16.h>
#include <math.h>

// Problem constants (CPUEfficientCausalAttention): B=2, S=2048, HIDDEN=1024, H=16, hd=64
#define HIDDEN 1024
#define HEADS 16
#define HDIM 64
#define BATCH 2
#define SEQ 2048
#define BHN (BATCH*HEADS)   // 32
#define MTOT (BATCH*SEQ)    // 4096

typedef __attribute__((ext_vector_type(8))) short short8;   // 8 bf16 = 4 VGPRs (MFMA A/B frag)
typedef __attribute__((ext_vector_type(4))) float floatx4;  // MFMA C/D frag

// global -> LDS direct (16B per lane; LDS dst is wave-uniform base, +lane*16 implicit)
#define GL2LDS(gsrc, ldst) __builtin_amdgcn_global_load_lds( \
    (const __attribute__((address_space(1))) void*)(gsrc), \
    (__attribute__((address_space(3))) void*)(ldst), 16, 0, 0)

__device__ __forceinline__ short f2bf(float f) {
  union { float f; unsigned u; } v; v.f = f;
  unsigned u = v.u;
  unsigned r = (u + 0x7fffu + ((u >> 16) & 1u)) >> 16;  // RNE
  return (short)r;
}

// One fused fp32->bf16 cast for x (1048576 vec4), qkv_w (786432), out_w (262144)
__global__ __launch_bounds__(256) void cvt3_f32_bf16(
    const float* __restrict__ a, const float* __restrict__ b, const float* __restrict__ c,
    short* __restrict__ oa, short* __restrict__ ob, short* __restrict__ oc) {
  int i = blockIdx.x * 256 + threadIdx.x;
  const float* src; short* dst; int j;
  if (i < 1048576)      { src = a; dst = oa; j = i; }
  else if (i < 1835008) { src = b; dst = ob; j = i - 1048576; }
  else                  { src = c; dst = oc; j = i - 1835008; }
  float4 f = reinterpret_cast<const float4*>(src)[j];
  short4 o;
  o.x = f2bf(f.x); o.y = f2bf(f.y); o.z = f2bf(f.z); o.w = f2bf(f.w);
  reinterpret_cast<short4*>(dst)[j] = o;
}

// C[M,N] = A[M,K] @ B[N,K]^T, bf16 in, fp32 accum.
// 128xBN tile, BK=32, 4 waves in 2x2, each wave 64x(BN/2).
// EPI==1 (BN=128): scatter qkv epilogue (q scaled by hd^-0.5*log2e, k row-major, v transposed)
// EPI==2: plain fp32 C row-major
template<int EPI, int BN>
__global__ __launch_bounds__(256) void gemm_bt(
    const short* __restrict__ A, const short* __restrict__ B,
    int M, int N, int K,
    float* __restrict__ outF,
    short* __restrict__ outQ, short* __restrict__ outK, short* __restrict__ outV)
{
  constexpr int WN = BN / 2;   // wave col extent
  constexpr int NI = BN / 32;  // 16-col tiles per wave
  __shared__ __align__(16) short As[128*32];
  __shared__ __align__(16) short Bs[BN*32];
  const int tid = threadIdx.x;
  const int wv = tid >> 6;
  const int lane = tid & 63;
  const int l15 = lane & 15;
  const int quad = lane >> 4;
  const int wm = wv >> 1, wn = wv & 1;
  const int row0 = blockIdx.y * 128, col0 = blockIdx.x * BN;

  floatx4 acc[4][NI];
#pragma unroll
  for (int i = 0; i < 4; i++)
#pragma unroll
    for (int j = 0; j < NI; j++) acc[i][j] = (floatx4){0.f, 0.f, 0.f, 0.f};

  for (int k0 = 0; k0 < K; k0 += 32) {
#pragma unroll
    for (int rd = 0; rd < 2; ++rd) {
      int chunk = rd * 256 + tid;
      int r = chunk >> 2, c = (chunk & 3) << 3;
      GL2LDS(A + (long)(row0 + r) * K + k0 + c, As + (rd * 256 + wv * 64) * 8);
    }
#pragma unroll
    for (int rd = 0; rd < BN / 64; ++rd) {
      int chunk = rd * 256 + tid;
      int r = chunk >> 2, c = (chunk & 3) << 3;
      GL2LDS(B + (long)(col0 + r) * K + k0 + c, Bs + (rd * 256 + wv * 64) * 8);
    }
    __syncthreads();

    short8 af[4], bfr[NI];
#pragma unroll
    for (int mi = 0; mi < 4; mi++)
      af[mi] = *(const short8*)(As + (wm * 64 + mi * 16 + l15) * 32 + quad * 8);
#pragma unroll
    for (int ni = 0; ni < NI; ni++)
      bfr[ni] = *(const short8*)(Bs + (wn * WN + ni * 16 + l15) * 32 + quad * 8);
#pragma unroll
    for (int mi = 0; mi < 4; mi++)
#pragma unroll
      for (int ni = 0; ni < NI; ni++)
        acc[mi][ni] = __builtin_amdgcn_mfma_f32_16x16x32_bf16(af[mi], bfr[ni], acc[mi][ni], 0, 0, 0);
    __syncthreads();
  }

  if (EPI == 2) {
#pragma unroll
    for (int mi = 0; mi < 4; mi++) {
      int rr = row0 + wm * 64 + mi * 16 + quad * 4;
#pragma unroll
      for (int ni = 0; ni < NI; ni++) {
        int cc = col0 + wn * WN + ni * 16 + l15;
#pragma unroll
        for (int r = 0; r < 4; r++)
          outF[(long)(rr + r) * N + cc] = acc[mi][ni][r];
      }
    }
  } else {
    // qkv scatter: j = t*1024 + h*64 + d ; i = b*2048 + s
#pragma unroll
    for (int mi = 0; mi < 4; mi++) {
      int rowg = row0 + wm * 64 + mi * 16 + quad * 4;
#pragma unroll
      for (int ni = 0; ni < NI; ni++) {
        int j = col0 + wn * WN + ni * 16 + l15;
        int t = j >> 10;
        int rem = j & 1023;
        int h = rem >> 6, d = rem & 63;
#pragma unroll
        for (int r = 0; r < 4; r++) {
          int i = rowg + r;
          int b = i >> 11, s = i & 2047;
          int bh = b * HEADS + h;
          float v = acc[mi][ni][r];
          // q scale = hd^-0.5 * log2(e) so flash can use raw v_exp_f32 (2^x)
          if (t == 0)      outQ[(bh * SEQ + s) * HDIM + d] = f2bf(v * 0.18033688011112042f);
          else if (t == 1) outK[(bh * SEQ + s) * HDIM + d] = f2bf(v);
          else             outV[(bh * HDIM + d) * SEQ + s] = f2bf(v);          // transposed
        }
      }
    }
  }
}

// Flash attention, barrier-free:
//  - K/V fragments loaded straight from global (L2-resident; fully coalesced 16B/lane).
//  - Scores computed TRANSPOSED (S^T = K.Q^T; Q's A-frag bytes double as the B-frag), so
//    each lane holds 4 consecutive kpos per q -> P written to LDS with ds_write_b64 (8/tile).
//  - Static-max softmax in exp2 domain (log2e folded into q); row-sum l via P @ ones MFMA.
//  - Uniform work: wave wv of block (bh,p) handles 16 q-rows of tile tL=31-p AND 16 of
//    tile tS=p (64-row tiles); small tile's kt range is a subset -> every wave = 34 half-tiles.
// grid (32 bh, 16 p), block 256 = 4 waves. LDS: 16 KB (P only). No __syncthreads.
__global__ __launch_bounds__(256, 2) void flash_attn(
    const short* __restrict__ qg, const short* __restrict__ kg,
    const short* __restrict__ vT, short* __restrict__ attn)
{
  __shared__ __align__(16) short Ps[4][32 * 64];
  const int tid = threadIdx.x;
  const int wv = tid >> 6, lane = tid & 63;
  const int l15 = lane & 15, quad = lane >> 4;
  const int bh = blockIdx.x;
  const int p  = blockIdx.y;
  const int tL = 31 - p, tS = p;
  int m0[2];
  m0[0] = tL * 64 + wv * 16;
  m0[1] = tS * 64 + wv * 16;
  const int swl = l15 & 7;
  short* Pw = &Ps[wv][0];

  // Q fragments (persistent). B-frag for S^T: col q = m0[mi]+l15, k(d) = kk*32+quad*8+j
  short8 aq[2][2];
#pragma unroll
  for (int mi = 0; mi < 2; mi++) {
    const short* qp = qg + (long)(bh * SEQ + m0[mi] + l15) * HDIM + quad * 8;
    aq[mi][0] = *(const short8*)qp;
    aq[mi][1] = *(const short8*)(qp + 32);
  }

  const short ONE = (short)0x3F80;  // bf16 1.0
  const short8 ones = {ONE, ONE, ONE, ONE, ONE, ONE, ONE, ONE};

  floatx4 o[2][4], lsum[2];
#pragma unroll
  for (int mi = 0; mi < 2; mi++) {
    lsum[mi] = (floatx4){0.f, 0.f, 0.f, 0.f};
#pragma unroll
    for (int nt = 0; nt < 4; nt++) o[mi][nt] = (floatx4){0.f, 0.f, 0.f, 0.f};
  }

  for (int kt = 0; kt <= tL; ++kt) {
    // K (A-frag: row kpos, k=d) and V^T (B-frag: col d, k=kpos) straight from global.
    short8 kf[4][2], vf[4][2];
#pragma unroll
    for (int nh = 0; nh < 4; nh++) {
      const short* kp = kg + (long)(bh * SEQ + kt * 64 + nh * 16 + l15) * HDIM + quad * 8;
      kf[nh][0] = *(const short8*)kp;
      kf[nh][1] = *(const short8*)(kp + 32);
      const short* vp = vT + (long)(bh * HDIM + nh * 16 + l15) * SEQ + kt * 64 + quad * 8;
      vf[nh][0] = *(const short8*)vp;
      vf[nh][1] = *(const short8*)(vp + 32);
    }

    const int nmi = (kt <= tS) ? 2 : 1;
    for (int mi = 0; mi < nmi; ++mi) {
      const int tmi = (mi == 0) ? tL : tS;
      const bool partial = (kt == tmi);      // wave-uniform
      const int qrow = m0[mi] + l15;

#pragma unroll
      for (int nh = 0; nh < 4; nh++) {
        // S^T tile: D[row=kpos(quad*4+r), col=q(l15)]
        floatx4 sc = (floatx4){0.f, 0.f, 0.f, 0.f};
        sc = __builtin_amdgcn_mfma_f32_16x16x32_bf16(kf[nh][0], aq[mi][0], sc, 0, 0, 0);
        sc = __builtin_amdgcn_mfma_f32_16x16x32_bf16(kf[nh][1], aq[mi][1], sc, 0, 0, 0);
        unsigned u[4];
#pragma unroll
        for (int r = 0; r < 4; r++) {
          float pe = __builtin_amdgcn_exp2f(sc[r]);
          if (partial) {
            const int kpos = kt * 64 + nh * 16 + quad * 4 + r;
            pe = (kpos <= qrow) ? pe : 0.f;
          }
          u[r] = __builtin_bit_cast(unsigned, pe) & 0xffff0000u;  // trunc to bf16
        }
        // pack 4 consecutive kpos (r=0..3) -> one b64 LDS write, 16B-chunk XOR swizzle
        uint2 wpk;
        wpk.x = (u[0] >> 16) | u[1];
        wpk.y = (u[2] >> 16) | u[3];
        *(uint2*)(Pw + (mi * 16 + l15) * 64 +
                  ((((nh << 1) + (quad >> 1)) ^ swl) << 3) + ((quad & 1) << 2)) = wpk;
      }
      // wave-local C->A layout transit; LDS ops are wave-ordered, no barrier needed
      __asm__ volatile("s_waitcnt lgkmcnt(0)" ::: "memory");
      const short* pr = Pw + (mi * 16 + l15) * 64;
      short8 pa0 = *(const short8*)(pr + (((0 + quad) ^ swl) << 3));
      short8 pa1 = *(const short8*)(pr + (((4 + quad) ^ swl) << 3));
      lsum[mi] = __builtin_amdgcn_mfma_f32_16x16x32_bf16(pa0, ones, lsum[mi], 0, 0, 0);
      lsum[mi] = __builtin_amdgcn_mfma_f32_16x16x32_bf16(pa1, ones, lsum[mi], 0, 0, 0);
#pragma unroll
      for (int nt = 0; nt < 4; nt++) {
        o[mi][nt] = __builtin_amdgcn_mfma_f32_16x16x32_bf16(pa0, vf[nt][0], o[mi][nt], 0, 0, 0);
        o[mi][nt] = __builtin_amdgcn_mfma_f32_16x16x32_bf16(pa1, vf[nt][1], o[mi][nt], 0, 0, 0);
      }
    }
  }

  const int b = bh >> 4, h = bh & 15;
#pragma unroll
  for (int mi = 0; mi < 2; mi++)
#pragma unroll
    for (int r = 0; r < 4; r++) {
      const float inv = 1.0f / lsum[mi][r];
      const int s = m0[mi] + quad * 4 + r;
#pragma unroll
      for (int nt = 0; nt < 4; nt++)
        attn[(long)(b * SEQ + s) * HIDDEN + h * HDIM + nt * 16 + l15] = f2bf(o[mi][nt][r] * inv);
    }
}

extern "C" void kernel_launch(void* const* d_in, const int* in_sizes, int n_in,
                              void* d_out, int out_size, void* d_ws, size_t ws_size,
                              hipStream_t stream) {
  const float* x     = (const float*)d_in[0];  // [2,2048,1024]
  const float* qkv_w = (const float*)d_in[1];  // [3072,1024]
  const float* out_w = (const float*)d_in[2];  // [1024,1024]
  float* out = (float*)d_out;                  // [2,2048,1024] fp32

  short* xb   = (short*)d_ws;                       // 4096*1024
  short* wqb  = xb  + MTOT * HIDDEN;                // 3072*1024
  short* wob  = wqb + 3 * HIDDEN * HIDDEN;          // 1024*1024
  short* qB   = wob + HIDDEN * HIDDEN;              // 32*2048*64
  short* kB   = qB  + BHN * SEQ * HDIM;
  short* vTB  = kB  + BHN * SEQ * HDIM;
  short* attn = vTB + BHN * SEQ * HDIM;             // 4096*1024

  // fused bf16 casts: (4096+3072+1024)*1024/4 = 2097152 vec4 -> 8192 blocks
  cvt3_f32_bf16<<<dim3(8192), dim3(256), 0, stream>>>(x, qkv_w, out_w, xb, wqb, wob);

  // QKV projection: M=4096, N=3072, K=1024
  gemm_bt<1, 128><<<dim3(3 * HIDDEN / 128, MTOT / 128), dim3(256), 0, stream>>>(
      xb, wqb, MTOT, 3 * HIDDEN, HIDDEN, nullptr, qB, kB, vTB);

  // causal attention: grid (bh, pair) -> 512 uniform-work blocks
  flash_attn<<<dim3(BHN, 16), dim3(256), 0, stream>>>(qB, kB, vTB, attn);

  // output projection: M=4096, N=1024, K=1024 (128x64 tiles -> 512 blocks, 2/CU)
  gemm_bt<2, 64><<<dim3(HIDDEN / 64, MTOT / 128), dim3(256), 0, stream>>>(
      attn, wob, MTOT, HIDDEN, HIDDEN, out, nullptr, nullptr, nullptr);
}

// Round 5
// 199.845 us; speedup vs baseline: 1.2375x; 1.2375x over previous
//
#include <hip/hip_runtime.h>
#include <hip/hip_bf16.h>
#include <math.h>

// Problem constants (CPUEfficientCausalAttention): B=2, S=2048, HIDDEN=1024, H=16, hd=64
#define HIDDEN 1024
#define HEADS 16
#define HDIM 64
#define BATCH 2
#define SEQ 2048
#define BHN (BATCH*HEADS)   // 32
#define MTOT (BATCH*SEQ)    // 4096

typedef __attribute__((ext_vector_type(8))) short short8;   // 8 bf16 (16x16x32 A/B frag)
typedef __attribute__((ext_vector_type(4))) short short4v;  // 4 bf16 (16x16x16 A/B frag)
typedef __attribute__((ext_vector_type(4))) float floatx4;  // MFMA C/D frag

// global -> LDS direct (16B per lane; LDS dst is wave-uniform base, +lane*16 implicit)
#define GL2LDS(gsrc, ldst) __builtin_amdgcn_global_load_lds( \
    (const __attribute__((address_space(1))) void*)(gsrc), \
    (__attribute__((address_space(3))) void*)(ldst), 16, 0, 0)

__device__ __forceinline__ short f2bf(float f) {
  union { float f; unsigned u; } v; v.f = f;
  unsigned u = v.u;
  unsigned r = (u + 0x7fffu + ((u >> 16) & 1u)) >> 16;  // RNE
  return (short)r;
}

// One fused fp32->bf16 cast for x (1048576 vec4), qkv_w (786432), out_w (262144)
__global__ __launch_bounds__(256) void cvt3_f32_bf16(
    const float* __restrict__ a, const float* __restrict__ b, const float* __restrict__ c,
    short* __restrict__ oa, short* __restrict__ ob, short* __restrict__ oc) {
  int i = blockIdx.x * 256 + threadIdx.x;
  const float* src; short* dst; int j;
  if (i < 1048576)      { src = a; dst = oa; j = i; }
  else if (i < 1835008) { src = b; dst = ob; j = i - 1048576; }
  else                  { src = c; dst = oc; j = i - 1835008; }
  float4 f = reinterpret_cast<const float4*>(src)[j];
  short4 o;
  o.x = f2bf(f.x); o.y = f2bf(f.y); o.z = f2bf(f.z); o.w = f2bf(f.w);
  reinterpret_cast<short4*>(dst)[j] = o;
}

// C[M,N] = A[M,K] @ B[N,K]^T, bf16 in, fp32 accum.
// 128xBN tile, BK=32, 4 waves in 2x2, each wave 64x(BN/2).
// EPI==1 (BN=128): scatter qkv epilogue (q scaled by hd^-0.5*log2e, k row-major, v transposed)
// EPI==2: plain fp32 C row-major
template<int EPI, int BN>
__global__ __launch_bounds__(256) void gemm_bt(
    const short* __restrict__ A, const short* __restrict__ B,
    int M, int N, int K,
    float* __restrict__ outF,
    short* __restrict__ outQ, short* __restrict__ outK, short* __restrict__ outV)
{
  constexpr int WN = BN / 2;   // wave col extent
  constexpr int NI = BN / 32;  // 16-col tiles per wave
  __shared__ __align__(16) short As[128*32];
  __shared__ __align__(16) short Bs[BN*32];
  const int tid = threadIdx.x;
  const int wv = tid >> 6;
  const int lane = tid & 63;
  const int l15 = lane & 15;
  const int quad = lane >> 4;
  const int wm = wv >> 1, wn = wv & 1;
  const int row0 = blockIdx.y * 128, col0 = blockIdx.x * BN;

  floatx4 acc[4][NI];
#pragma unroll
  for (int i = 0; i < 4; i++)
#pragma unroll
    for (int j = 0; j < NI; j++) acc[i][j] = (floatx4){0.f, 0.f, 0.f, 0.f};

  for (int k0 = 0; k0 < K; k0 += 32) {
#pragma unroll
    for (int rd = 0; rd < 2; ++rd) {
      int chunk = rd * 256 + tid;
      int r = chunk >> 2, c = (chunk & 3) << 3;
      GL2LDS(A + (long)(row0 + r) * K + k0 + c, As + (rd * 256 + wv * 64) * 8);
    }
#pragma unroll
    for (int rd = 0; rd < BN / 64; ++rd) {
      int chunk = rd * 256 + tid;
      int r = chunk >> 2, c = (chunk & 3) << 3;
      GL2LDS(B + (long)(col0 + r) * K + k0 + c, Bs + (rd * 256 + wv * 64) * 8);
    }
    __syncthreads();

    short8 af[4], bfr[NI];
#pragma unroll
    for (int mi = 0; mi < 4; mi++)
      af[mi] = *(const short8*)(As + (wm * 64 + mi * 16 + l15) * 32 + quad * 8);
#pragma unroll
    for (int ni = 0; ni < NI; ni++)
      bfr[ni] = *(const short8*)(Bs + (wn * WN + ni * 16 + l15) * 32 + quad * 8);
#pragma unroll
    for (int mi = 0; mi < 4; mi++)
#pragma unroll
      for (int ni = 0; ni < NI; ni++)
        acc[mi][ni] = __builtin_amdgcn_mfma_f32_16x16x32_bf16(af[mi], bfr[ni], acc[mi][ni], 0, 0, 0);
    __syncthreads();
  }

  if (EPI == 2) {
#pragma unroll
    for (int mi = 0; mi < 4; mi++) {
      int rr = row0 + wm * 64 + mi * 16 + quad * 4;
#pragma unroll
      for (int ni = 0; ni < NI; ni++) {
        int cc = col0 + wn * WN + ni * 16 + l15;
#pragma unroll
        for (int r = 0; r < 4; r++)
          outF[(long)(rr + r) * N + cc] = acc[mi][ni][r];
      }
    }
  } else {
    // qkv scatter: j = t*1024 + h*64 + d ; i = b*2048 + s
#pragma unroll
    for (int mi = 0; mi < 4; mi++) {
      int rowg = row0 + wm * 64 + mi * 16 + quad * 4;
#pragma unroll
      for (int ni = 0; ni < NI; ni++) {
        int j = col0 + wn * WN + ni * 16 + l15;
        int t = j >> 10;
        int rem = j & 1023;
        int h = rem >> 6, d = rem & 63;
#pragma unroll
        for (int r = 0; r < 4; r++) {
          int i = rowg + r;
          int b = i >> 11, s = i & 2047;
          int bh = b * HEADS + h;
          float v = acc[mi][ni][r];
          // q scale = hd^-0.5 * log2(e) so flash can use raw v_exp_f32 (2^x)
          if (t == 0)      outQ[(bh * SEQ + s) * HDIM + d] = f2bf(v * 0.18033688011112042f);
          else if (t == 1) outK[(bh * SEQ + s) * HDIM + d] = f2bf(v);
          else             outV[(bh * HDIM + d) * SEQ + s] = f2bf(v);          // transposed
        }
      }
    }
  }
}

// K/V tile staging: 64 kpos x 64 d (K) and 64 d x 64 kpos (V^T), XOR-swizzled 8-short
// chunks: LDS slot (row r, chunk c') holds global chunk c' ^ (r&7). Swizzle applied on
// the per-lane SOURCE address since global_load_lds's LDS dst is fixed lane*16.
__device__ __forceinline__ void stage_kv(const short* __restrict__ kg,
                                         const short* __restrict__ vT,
                                         int bh, int kt, short* KsB, short* VsB,
                                         int tid, int wv) {
#pragma unroll
  for (int i = 0; i < 2; ++i) {
    int slot = i * 256 + tid;
    int r = slot >> 3;
    int sc = ((slot & 7) ^ (r & 7)) << 3;
    GL2LDS(kg + (bh * SEQ + kt * 64 + r) * HDIM + sc, KsB + (i * 256 + wv * 64) * 8);
    GL2LDS(vT + (bh * HDIM + r) * SEQ + kt * 64 + sc, VsB + (i * 256 + wv * 64) * 8);
  }
}

// Flash attention v5: staged K/V (double-buffered GL2LDS, as R3) + REGISTER-ONLY P.
//  - S^T = K.Q^T via 16x16x32 (Q's A-frag bytes double as B-frag). S^T C-layout
//    (q=l15, kpos=quad*4+r) IS the A-operand layout of v_mfma_f32_16x16x16_bf16
//    (m=l15, k=quad*4+j) -> P never touches LDS: exp2, mask, pack bf16 pairs, MFMA.
//  - Row-sum l via P @ ones (K=16 MFMA). Static-max softmax in exp2 domain.
//  - V B-frags (k=kpos groups of 4) read from V^T tile as swizzled ds_read_b64.
// grid (16 pair, 32 bh), block 256 = 4 waves x 32 q-rows; t = bh<16 ? 15-x : x pairing.
// LDS: 32 KB (K/V double buffer only). No P LDS, no lgkmcnt(0) drains.
__global__ __launch_bounds__(256, 3) void flash_attn(
    const short* __restrict__ qg, const short* __restrict__ kg,
    const short* __restrict__ vT, short* __restrict__ attn)
{
  __shared__ __align__(16) short Ks[2][64 * 64];
  __shared__ __align__(16) short Vs[2][64 * 64];

  const int tid = threadIdx.x;
  const int wv = tid >> 6, lane = tid & 63;
  const int l15 = lane & 15, quad = lane >> 4;
  const int bh = blockIdx.y;
  const int t = (bh < 16) ? (15 - (int)blockIdx.x) : (int)blockIdx.x;
  const int m0 = t * 128 + wv * 32;         // wave's first q row
  const int swl = l15 & 7;

  // Q frags (persistent): B-operand for S^T: n=q=m0+mi*16+l15, k=d=kk*32+quad*8+j
  short8 aq[2][2];
#pragma unroll
  for (int mi = 0; mi < 2; mi++) {
    const short* qp = qg + (long)(bh * SEQ + m0 + mi * 16 + l15) * HDIM + quad * 8;
    aq[mi][0] = *(const short8*)qp;
    aq[mi][1] = *(const short8*)(qp + 32);
  }

  const short ONE = (short)0x3F80;  // bf16 1.0
  const short4v ones4 = {ONE, ONE, ONE, ONE};

  floatx4 o[2][4], lsum[2];
#pragma unroll
  for (int mi = 0; mi < 2; mi++) {
    lsum[mi] = (floatx4){0.f, 0.f, 0.f, 0.f};
#pragma unroll
    for (int nt = 0; nt < 4; nt++) o[mi][nt] = (floatx4){0.f, 0.f, 0.f, 0.f};
  }

  const int ntiles = 2 * t + 2;
  stage_kv(kg, vT, bh, 0, Ks[0], Vs[0], tid, wv);

  for (int kt = 0; kt < ntiles; ++kt) {
    __syncthreads();                         // drains GL2LDS (vmcnt 0) + syncs: buf[kt&1] ready
    const int buf = kt & 1;
    if (kt + 1 < ntiles)                     // prefetch next tile; drained at NEXT barrier
      stage_kv(kg, vT, bh, kt + 1, Ks[buf ^ 1], Vs[buf ^ 1], tid, wv);

    if (kt * 64 <= m0 + 31) {                // tile intersects this wave's causal range
      const short* KsB = Ks[buf];
      const short* VsB = Vs[buf];

      // ---- S^T = K . Q^T (16x16x32): D[row=kpos(quad*4+r)][col=q(l15)] ----
      floatx4 sc[2][4];
#pragma unroll
      for (int mi = 0; mi < 2; mi++)
#pragma unroll
        for (int nh = 0; nh < 4; nh++) sc[mi][nh] = (floatx4){0.f, 0.f, 0.f, 0.f};
#pragma unroll
      for (int nh = 0; nh < 4; nh++) {
        const short* kp = KsB + (nh * 16 + l15) * 64;
        short8 kf0 = *(const short8*)(kp + ((quad ^ swl) << 3));         // A: m=kpos, k=d 0..31
        short8 kf1 = *(const short8*)(kp + (((4 + quad) ^ swl) << 3));   // k=d 32..63
#pragma unroll
        for (int mi = 0; mi < 2; mi++) {
          sc[mi][nh] = __builtin_amdgcn_mfma_f32_16x16x32_bf16(kf0, aq[mi][0], sc[mi][nh], 0, 0, 0);
          sc[mi][nh] = __builtin_amdgcn_mfma_f32_16x16x32_bf16(kf1, aq[mi][1], sc[mi][nh], 0, 0, 0);
        }
      }

      // ---- softmax (static max, exp2 domain) + pack P into K=16 A-frags (registers) ----
      short4v pa[2][4];
#pragma unroll
      for (int mi = 0; mi < 2; mi++) {
        const int qrow = m0 + mi * 16 + l15;
        const bool full = (kt * 64 + 63) <= (m0 + mi * 16);   // wave-uniform per mi
#pragma unroll
        for (int nh = 0; nh < 4; nh++) {
          unsigned u[4];
#pragma unroll
          for (int r = 0; r < 4; r++) {
            float pe = __builtin_amdgcn_exp2f(sc[mi][nh][r]);
            if (!full) {
              const int kpos = kt * 64 + nh * 16 + quad * 4 + r;
              pe = (kpos <= qrow) ? pe : 0.f;
            }
            u[r] = __builtin_bit_cast(unsigned, pe) & 0xffff0000u;  // trunc to bf16
          }
          uint2 w;
          w.x = (u[0] >> 16) | u[1];   // k = quad*4 + {0,1}
          w.y = (u[2] >> 16) | u[3];   // k = quad*4 + {2,3}
          pa[mi][nh] = __builtin_bit_cast(short4v, w);
        }
      }

      // ---- P @ V and P @ ones via 16x16x16 MFMA (P direct from registers) ----
#pragma unroll
      for (int kk = 0; kk < 4; kk++) {
        short4v bv[4];
#pragma unroll
        for (int nt = 0; nt < 4; nt++) {
          const int ch = (kk * 2 + (quad >> 1)) ^ swl;   // 16B-chunk swizzle
          bv[nt] = *(const short4v*)(VsB + (nt * 16 + l15) * 64 + (ch << 3) + ((quad & 1) << 2));
        }
#pragma unroll
        for (int mi = 0; mi < 2; mi++) {
          lsum[mi] = __builtin_amdgcn_mfma_f32_16x16x16bf16_1k(pa[mi][kk], ones4, lsum[mi], 0, 0, 0);
#pragma unroll
          for (int nt = 0; nt < 4; nt++)
            o[mi][nt] = __builtin_amdgcn_mfma_f32_16x16x16bf16_1k(pa[mi][kk], bv[nt], o[mi][nt], 0, 0, 0);
        }
      }
    }
  }

  const int b = bh >> 4, h = bh & 15;
#pragma unroll
  for (int mi = 0; mi < 2; mi++)
#pragma unroll
    for (int r = 0; r < 4; r++) {
      const float inv = 1.0f / lsum[mi][r];
      const int s = m0 + mi * 16 + quad * 4 + r;
#pragma unroll
      for (int nt = 0; nt < 4; nt++)
        attn[(long)(b * SEQ + s) * HIDDEN + h * HDIM + nt * 16 + l15] = f2bf(o[mi][nt][r] * inv);
    }
}

extern "C" void kernel_launch(void* const* d_in, const int* in_sizes, int n_in,
                              void* d_out, int out_size, void* d_ws, size_t ws_size,
                              hipStream_t stream) {
  const float* x     = (const float*)d_in[0];  // [2,2048,1024]
  const float* qkv_w = (const float*)d_in[1];  // [3072,1024]
  const float* out_w = (const float*)d_in[2];  // [1024,1024]
  float* out = (float*)d_out;                  // [2,2048,1024] fp32

  short* xb   = (short*)d_ws;                       // 4096*1024
  short* wqb  = xb  + MTOT * HIDDEN;                // 3072*1024
  short* wob  = wqb + 3 * HIDDEN * HIDDEN;          // 1024*1024
  short* qB   = wob + HIDDEN * HIDDEN;              // 32*2048*64
  short* kB   = qB  + BHN * SEQ * HDIM;
  short* vTB  = kB  + BHN * SEQ * HDIM;
  short* attn = vTB + BHN * SEQ * HDIM;             // 4096*1024

  // fused bf16 casts: (4096+3072+1024)*1024/4 = 2097152 vec4 -> 8192 blocks
  cvt3_f32_bf16<<<dim3(8192), dim3(256), 0, stream>>>(x, qkv_w, out_w, xb, wqb, wob);

  // QKV projection: M=4096, N=3072, K=1024
  gemm_bt<1, 128><<<dim3(3 * HIDDEN / 128, MTOT / 128), dim3(256), 0, stream>>>(
      xb, wqb, MTOT, 3 * HIDDEN, HIDDEN, nullptr, qB, kB, vTB);

  // causal attention: grid (pair, bh), paired load balance
  flash_attn<<<dim3(SEQ / 128, BHN), dim3(256), 0, stream>>>(qB, kB, vTB, attn);

  // output projection: M=4096, N=1024, K=1024 (128x64 tiles -> 512 blocks)
  gemm_bt<2, 64><<<dim3(HIDDEN / 64, MTOT / 128), dim3(256), 0, stream>>>(
      attn, wob, MTOT, HIDDEN, HIDDEN, out, nullptr, nullptr, nullptr);
}

// Round 6
// 180.412 us; speedup vs baseline: 1.3708x; 1.1077x over previous
//
#include <hip/hip_runtime.h>
#include <hip/hip_bf16.h>
#include <math.h>

// Problem constants (CPUEfficientCausalAttention): B=2, S=2048, HIDDEN=1024, H=16, hd=64
#define HIDDEN 1024
#define HEADS 16
#define HDIM 64
#define BATCH 2
#define SEQ 2048
#define BHN (BATCH*HEADS)   // 32
#define MTOT (BATCH*SEQ)    // 4096

typedef __attribute__((ext_vector_type(8))) short short8;   // 8 bf16 (16x16x32 A/B frag)
typedef __attribute__((ext_vector_type(4))) short short4v;  // 4 bf16 (16x16x16 A/B frag)
typedef __attribute__((ext_vector_type(4))) float floatx4;  // MFMA C/D frag

// global -> LDS direct (16B per lane; LDS dst is wave-uniform base, +lane*16 implicit)
#define GL2LDS(gsrc, ldst) __builtin_amdgcn_global_load_lds( \
    (const __attribute__((address_space(1))) void*)(gsrc), \
    (__attribute__((address_space(3))) void*)(ldst), 16, 0, 0)

__device__ __forceinline__ short f2bf(float f) {
  union { float f; unsigned u; } v; v.f = f;
  unsigned u = v.u;
  unsigned r = (u + 0x7fffu + ((u >> 16) & 1u)) >> 16;  // RNE
  return (short)r;
}

// One fused fp32->bf16 cast for x (1048576 vec4), qkv_w (786432), out_w (262144)
__global__ __launch_bounds__(256) void cvt3_f32_bf16(
    const float* __restrict__ a, const float* __restrict__ b, const float* __restrict__ c,
    short* __restrict__ oa, short* __restrict__ ob, short* __restrict__ oc) {
  int i = blockIdx.x * 256 + threadIdx.x;
  const float* src; short* dst; int j;
  if (i < 1048576)      { src = a; dst = oa; j = i; }
  else if (i < 1835008) { src = b; dst = ob; j = i - 1048576; }
  else                  { src = c; dst = oc; j = i - 1835008; }
  float4 f = reinterpret_cast<const float4*>(src)[j];
  short4 o;
  o.x = f2bf(f.x); o.y = f2bf(f.y); o.z = f2bf(f.z); o.w = f2bf(f.w);
  reinterpret_cast<short4*>(dst)[j] = o;
}

// C[M,N] = A[M,K] @ B[N,K]^T, bf16 in, fp32 accum.
// 128xBN tile, BK=64 (XOR-swizzled LDS rows of 128B keep b128 reads bank-minimal),
// 4 waves in 2x2, each wave 64x(BN/2).
// EPI==1 (BN=128): scatter qkv epilogue (q scaled by hd^-0.5*log2e, k row-major, v transposed)
// EPI==2: plain fp32 C row-major
template<int EPI, int BN>
__global__ __launch_bounds__(256) void gemm_bt(
    const short* __restrict__ A, const short* __restrict__ B,
    int M, int N, int K,
    float* __restrict__ outF,
    short* __restrict__ outQ, short* __restrict__ outK, short* __restrict__ outV)
{
  constexpr int WN = BN / 2;   // wave col extent
  constexpr int NI = BN / 32;  // 16-col tiles per wave
  __shared__ __align__(16) short As[128*64];
  __shared__ __align__(16) short Bs[BN*64];
  const int tid = threadIdx.x;
  const int wv = tid >> 6;
  const int lane = tid & 63;
  const int l15 = lane & 15;
  const int quad = lane >> 4;
  const int swl = l15 & 7;
  const int wm = wv >> 1, wn = wv & 1;
  const int row0 = blockIdx.y * 128, col0 = blockIdx.x * BN;

  floatx4 acc[4][NI];
#pragma unroll
  for (int i = 0; i < 4; i++)
#pragma unroll
    for (int j = 0; j < NI; j++) acc[i][j] = (floatx4){0.f, 0.f, 0.f, 0.f};

  for (int k0 = 0; k0 < K; k0 += 64) {
    // stage A [128][64] (1024 16B-chunks) and B [BN][64], XOR-swizzled on source col
#pragma unroll
    for (int rd = 0; rd < 4; ++rd) {
      int chunk = rd * 256 + tid;
      int r = chunk >> 3, c = ((chunk & 7) ^ (r & 7)) << 3;
      GL2LDS(A + (long)(row0 + r) * K + k0 + c, As + (rd * 256 + wv * 64) * 8);
    }
#pragma unroll
    for (int rd = 0; rd < BN / 32; ++rd) {
      int chunk = rd * 256 + tid;
      int r = chunk >> 3, c = ((chunk & 7) ^ (r & 7)) << 3;
      GL2LDS(B + (long)(col0 + r) * K + k0 + c, Bs + (rd * 256 + wv * 64) * 8);
    }
    __syncthreads();

    short8 af[4][2], bfr[NI][2];
#pragma unroll
    for (int mi = 0; mi < 4; mi++) {
      const short* ap = As + (wm * 64 + mi * 16 + l15) * 64;
#pragma unroll
      for (int kk = 0; kk < 2; kk++)
        af[mi][kk] = *(const short8*)(ap + (((kk * 4 + quad) ^ swl) << 3));
    }
#pragma unroll
    for (int ni = 0; ni < NI; ni++) {
      const short* bp = Bs + (wn * WN + ni * 16 + l15) * 64;
#pragma unroll
      for (int kk = 0; kk < 2; kk++)
        bfr[ni][kk] = *(const short8*)(bp + (((kk * 4 + quad) ^ swl) << 3));
    }
#pragma unroll
    for (int mi = 0; mi < 4; mi++)
#pragma unroll
      for (int ni = 0; ni < NI; ni++)
#pragma unroll
        for (int kk = 0; kk < 2; kk++)
          acc[mi][ni] = __builtin_amdgcn_mfma_f32_16x16x32_bf16(af[mi][kk], bfr[ni][kk], acc[mi][ni], 0, 0, 0);
    __syncthreads();
  }

  if (EPI == 2) {
#pragma unroll
    for (int mi = 0; mi < 4; mi++) {
      int rr = row0 + wm * 64 + mi * 16 + quad * 4;
#pragma unroll
      for (int ni = 0; ni < NI; ni++) {
        int cc = col0 + wn * WN + ni * 16 + l15;
#pragma unroll
        for (int r = 0; r < 4; r++)
          outF[(long)(rr + r) * N + cc] = acc[mi][ni][r];
      }
    }
  } else {
    // qkv scatter: j = t*1024 + h*64 + d ; i = b*2048 + s
#pragma unroll
    for (int mi = 0; mi < 4; mi++) {
      int rowg = row0 + wm * 64 + mi * 16 + quad * 4;
#pragma unroll
      for (int ni = 0; ni < NI; ni++) {
        int j = col0 + wn * WN + ni * 16 + l15;
        int t = j >> 10;
        int rem = j & 1023;
        int h = rem >> 6, d = rem & 63;
#pragma unroll
        for (int r = 0; r < 4; r++) {
          int i = rowg + r;
          int b = i >> 11, s = i & 2047;
          int bh = b * HEADS + h;
          float v = acc[mi][ni][r];
          // q scale = hd^-0.5 * log2(e) so flash can use raw v_exp_f32 (2^x)
          if (t == 0)      outQ[(bh * SEQ + s) * HDIM + d] = f2bf(v * 0.18033688011112042f);
          else if (t == 1) outK[(bh * SEQ + s) * HDIM + d] = f2bf(v);
          else             outV[(bh * HDIM + d) * SEQ + s] = f2bf(v);          // transposed
        }
      }
    }
  }
}

// K/V tile staging for 128-thread blocks: 64x64 K and 64x64 V^T, XOR-swizzled 16B chunks.
__device__ __forceinline__ void stage_kv(const short* __restrict__ kg,
                                         const short* __restrict__ vT,
                                         int bh, int kt, short* KsB, short* VsB,
                                         int tid, int wv) {
#pragma unroll
  for (int i = 0; i < 4; ++i) {
    int slot = i * 128 + tid;                 // 0..511
    int r = slot >> 3;
    int sc = ((slot & 7) ^ (r & 7)) << 3;
    GL2LDS(kg + (bh * SEQ + kt * 64 + r) * HDIM + sc, KsB + (i * 128 + wv * 64) * 8);
    GL2LDS(vT + (bh * HDIM + r) * SEQ + kt * 64 + sc, VsB + (i * 128 + wv * 64) * 8);
  }
}

// Flash attention v6: 64-row blocks, 2 waves (32 q-rows each) -> BOTH waves active on
// EVERY k-tile (no idle barrier waits), 1024 blocks = 4/CU, global LPT (rt = 31-y).
//  - staged K/V double-buffered via GL2LDS (R3/R5 structure)
//  - S^T = K.Q^T (16x16x32); S^T C-layout == K=16 A-layout -> P stays in registers
//  - static-max softmax, exp2 domain (log2e folded into q); l via P @ ones
// LDS: 32 KB. VGPR ~64.
__global__ __launch_bounds__(128, 2) void flash_attn(
    const short* __restrict__ qg, const short* __restrict__ kg,
    const short* __restrict__ vT, short* __restrict__ attn)
{
  __shared__ __align__(16) short Ks[2][64 * 64];
  __shared__ __align__(16) short Vs[2][64 * 64];

  const int tid = threadIdx.x;
  const int wv = tid >> 6, lane = tid & 63;
  const int l15 = lane & 15, quad = lane >> 4;
  const int bh = blockIdx.x;
  const int rt = 31 - (int)blockIdx.y;      // longest blocks dispatch first (global LPT)
  const int m0 = rt * 64 + wv * 32;         // wave's first q row
  const int swl = l15 & 7;

  // Q frags (persistent): B-operand for S^T: n=q=m0+mi*16+l15, k=d=kk*32+quad*8+j
  short8 aq[2][2];
#pragma unroll
  for (int mi = 0; mi < 2; mi++) {
    const short* qp = qg + (long)(bh * SEQ + m0 + mi * 16 + l15) * HDIM + quad * 8;
    aq[mi][0] = *(const short8*)qp;
    aq[mi][1] = *(const short8*)(qp + 32);
  }

  const short ONE = (short)0x3F80;  // bf16 1.0
  const short4v ones4 = {ONE, ONE, ONE, ONE};

  floatx4 o[2][4], lsum[2];
#pragma unroll
  for (int mi = 0; mi < 2; mi++) {
    lsum[mi] = (floatx4){0.f, 0.f, 0.f, 0.f};
#pragma unroll
    for (int nt = 0; nt < 4; nt++) o[mi][nt] = (floatx4){0.f, 0.f, 0.f, 0.f};
  }

  const int ntiles = rt + 1;
  stage_kv(kg, vT, bh, 0, Ks[0], Vs[0], tid, wv);

  for (int kt = 0; kt < ntiles; ++kt) {
    __syncthreads();                         // drains GL2LDS (vmcnt 0) + syncs: buf[kt&1] ready
    const int buf = kt & 1;
    if (kt + 1 < ntiles)                     // prefetch next tile; drained at NEXT barrier
      stage_kv(kg, vT, bh, kt + 1, Ks[buf ^ 1], Vs[buf ^ 1], tid, wv);

    const short* KsB = Ks[buf];
    const short* VsB = Vs[buf];

    // ---- S^T = K . Q^T (16x16x32): D[row=kpos(quad*4+r)][col=q(l15)] ----
    floatx4 sc[2][4];
#pragma unroll
    for (int mi = 0; mi < 2; mi++)
#pragma unroll
      for (int nh = 0; nh < 4; nh++) sc[mi][nh] = (floatx4){0.f, 0.f, 0.f, 0.f};
#pragma unroll
    for (int nh = 0; nh < 4; nh++) {
      const short* kp = KsB + (nh * 16 + l15) * 64;
      short8 kf0 = *(const short8*)(kp + ((quad ^ swl) << 3));         // A: m=kpos, k=d 0..31
      short8 kf1 = *(const short8*)(kp + (((4 + quad) ^ swl) << 3));   // k=d 32..63
#pragma unroll
      for (int mi = 0; mi < 2; mi++) {
        sc[mi][nh] = __builtin_amdgcn_mfma_f32_16x16x32_bf16(kf0, aq[mi][0], sc[mi][nh], 0, 0, 0);
        sc[mi][nh] = __builtin_amdgcn_mfma_f32_16x16x32_bf16(kf1, aq[mi][1], sc[mi][nh], 0, 0, 0);
      }
    }

    // ---- softmax (static max, exp2 domain) + pack P into K=16 A-frags (registers) ----
    short4v pa[2][4];
#pragma unroll
    for (int mi = 0; mi < 2; mi++) {
      const int qrow = m0 + mi * 16 + l15;
      const bool full = (kt * 64 + 63) <= (m0 + mi * 16);   // wave-uniform per mi
#pragma unroll
      for (int nh = 0; nh < 4; nh++) {
        unsigned u[4];
#pragma unroll
        for (int r = 0; r < 4; r++) {
          float pe = __builtin_amdgcn_exp2f(sc[mi][nh][r]);
          if (!full) {
            const int kpos = kt * 64 + nh * 16 + quad * 4 + r;
            pe = (kpos <= qrow) ? pe : 0.f;
          }
          u[r] = __builtin_bit_cast(unsigned, pe) & 0xffff0000u;  // trunc to bf16
        }
        uint2 w;
        w.x = (u[0] >> 16) | u[1];   // k = quad*4 + {0,1}
        w.y = (u[2] >> 16) | u[3];   // k = quad*4 + {2,3}
        pa[mi][nh] = __builtin_bit_cast(short4v, w);
      }
    }

    // ---- P @ V and P @ ones via 16x16x16 MFMA (P direct from registers) ----
#pragma unroll
    for (int kk = 0; kk < 4; kk++) {
      short4v bv[4];
#pragma unroll
      for (int nt = 0; nt < 4; nt++) {
        const int ch = (kk * 2 + (quad >> 1)) ^ swl;   // 16B-chunk swizzle
        bv[nt] = *(const short4v*)(VsB + (nt * 16 + l15) * 64 + (ch << 3) + ((quad & 1) << 2));
      }
#pragma unroll
      for (int mi = 0; mi < 2; mi++) {
        lsum[mi] = __builtin_amdgcn_mfma_f32_16x16x16bf16_1k(pa[mi][kk], ones4, lsum[mi], 0, 0, 0);
#pragma unroll
        for (int nt = 0; nt < 4; nt++)
          o[mi][nt] = __builtin_amdgcn_mfma_f32_16x16x16bf16_1k(pa[mi][kk], bv[nt], o[mi][nt], 0, 0, 0);
      }
    }
  }

  const int b = bh >> 4, h = bh & 15;
#pragma unroll
  for (int mi = 0; mi < 2; mi++)
#pragma unroll
    for (int r = 0; r < 4; r++) {
      const float inv = 1.0f / lsum[mi][r];
      const int s = m0 + mi * 16 + quad * 4 + r;
#pragma unroll
      for (int nt = 0; nt < 4; nt++)
        attn[(long)(b * SEQ + s) * HIDDEN + h * HDIM + nt * 16 + l15] = f2bf(o[mi][nt][r] * inv);
    }
}

extern "C" void kernel_launch(void* const* d_in, const int* in_sizes, int n_in,
                              void* d_out, int out_size, void* d_ws, size_t ws_size,
                              hipStream_t stream) {
  const float* x     = (const float*)d_in[0];  // [2,2048,1024]
  const float* qkv_w = (const float*)d_in[1];  // [3072,1024]
  const float* out_w = (const float*)d_in[2];  // [1024,1024]
  float* out = (float*)d_out;                  // [2,2048,1024] fp32

  short* xb   = (short*)d_ws;                       // 4096*1024
  short* wqb  = xb  + MTOT * HIDDEN;                // 3072*1024
  short* wob  = wqb + 3 * HIDDEN * HIDDEN;          // 1024*1024
  short* qB   = wob + HIDDEN * HIDDEN;              // 32*2048*64
  short* kB   = qB  + BHN * SEQ * HDIM;
  short* vTB  = kB  + BHN * SEQ * HDIM;
  short* attn = vTB + BHN * SEQ * HDIM;             // 4096*1024

  // fused bf16 casts: (4096+3072+1024)*1024/4 = 2097152 vec4 -> 8192 blocks
  cvt3_f32_bf16<<<dim3(8192), dim3(256), 0, stream>>>(x, qkv_w, out_w, xb, wqb, wob);

  // QKV projection: M=4096, N=3072, K=1024, BK=64
  gemm_bt<1, 128><<<dim3(3 * HIDDEN / 128, MTOT / 128), dim3(256), 0, stream>>>(
      xb, wqb, MTOT, 3 * HIDDEN, HIDDEN, nullptr, qB, kB, vTB);

  // causal attention: 64-row 2-wave blocks, global LPT order
  flash_attn<<<dim3(BHN, SEQ / 64), dim3(128), 0, stream>>>(qB, kB, vTB, attn);

  // output projection: M=4096, N=1024, K=1024 (128x64 tiles -> 512 blocks), BK=64
  gemm_bt<2, 64><<<dim3(HIDDEN / 64, MTOT / 128), dim3(256), 0, stream>>>(
      attn, wob, MTOT, HIDDEN, HIDDEN, out, nullptr, nullptr, nullptr);
}